// Round 6
// baseline (511.657 us; speedup 1.0000x reference)
//
#include <hip/hip_runtime.h>
#include <math.h>

// Problem constants: B=64, K=1000, NPC=256, D=768, k=16, S=10
#define BQ   64
#define KC   1000
#define NPC  256
#define DIM  768
#define TOPK 16
#define NS   10

#define NEG_INF (-__builtin_inff())

#define DOT12(acc, A, Bv) \
    acc = fmaf(A.x, Bv.x, acc); acc = fmaf(A.y, Bv.y, acc); \
    acc = fmaf(A.z, Bv.z, acc); acc = fmaf(A.w, Bv.w, acc);

// ---------- Kernel A: normalize queries -> qn ; blocks 0..3 also zero cnt[] ----------
__global__ void knorm_q(const float* __restrict__ q, float* __restrict__ qn,
                        int* __restrict__ cnt) {
    int b = blockIdx.x, t = threadIdx.x;
    if (b < 4 && t < 250) cnt[b * 250 + t] = 0;
    const float* row = q + b * DIM;
    float v0 = row[t], v1 = row[t + 256], v2 = row[t + 512];
    __shared__ float red[256];
    red[t] = v0 * v0 + v1 * v1 + v2 * v2;
    __syncthreads();
    for (int off = 128; off; off >>= 1) {
        if (t < off) red[t] += red[t + off];
        __syncthreads();
    }
    float scale = 1.0f / fmaxf(sqrtf(red[0]), 1e-12f);
    qn[b * DIM + t]       = v0 * scale;
    qn[b * DIM + t + 256] = v1 * scale;
    qn[b * DIM + t + 512] = v2 * scale;
}

// ---------- Kernel B: cos_c[b][k] = dot(qn[b], centers[k]) / |centers[k]| ----------
__global__ void kcenter_scores(const float* __restrict__ qn,
                               const float* __restrict__ centers,
                               float* __restrict__ cosc) {
    int wave = threadIdx.x >> 6, lane = threadIdx.x & 63;
    int cblk = blockIdx.x >> 2, qg = blockIdx.x & 3;
    int k0 = cblk * 4 + wave;                    // 250*4 = 1000 exactly
    const float4* cp = (const float4*)(centers + (size_t)k0 * DIM);
    float4 c0 = cp[lane], c1 = cp[lane + 64], c2 = cp[lane + 128];
    float sq = 0.f;
    DOT12(sq, c0, c0); DOT12(sq, c1, c1); DOT12(sq, c2, c2);
    for (int off = 1; off < 64; off <<= 1) sq += __shfl_xor(sq, off);
    float inv = 1.0f / fmaxf(sqrtf(sq), 1e-12f);
    int b0 = qg * 16;
    for (int i = 0; i < 16; i += 4) {
        const float4* qa = (const float4*)(qn + (size_t)(b0 + i + 0) * DIM);
        const float4* qb = (const float4*)(qn + (size_t)(b0 + i + 1) * DIM);
        const float4* qc = (const float4*)(qn + (size_t)(b0 + i + 2) * DIM);
        const float4* qd = (const float4*)(qn + (size_t)(b0 + i + 3) * DIM);
        float4 a0 = qa[lane], a1 = qa[lane + 64], a2 = qa[lane + 128];
        float4 e0 = qb[lane], e1 = qb[lane + 64], e2 = qb[lane + 128];
        float4 f0 = qc[lane], f1 = qc[lane + 64], f2 = qc[lane + 128];
        float4 g0 = qd[lane], g1 = qd[lane + 64], g2 = qd[lane + 128];
        float dA = 0.f, dB = 0.f, dC = 0.f, dD = 0.f;
        DOT12(dA, a0, c0); DOT12(dA, a1, c1); DOT12(dA, a2, c2);
        DOT12(dB, e0, c0); DOT12(dB, e1, c1); DOT12(dB, e2, c2);
        DOT12(dC, f0, c0); DOT12(dC, f1, c1); DOT12(dC, f2, c2);
        DOT12(dD, g0, c0); DOT12(dD, g1, c1); DOT12(dD, g2, c2);
        for (int off = 1; off < 64; off <<= 1) {
            dA += __shfl_xor(dA, off);
            dB += __shfl_xor(dB, off);
            dC += __shfl_xor(dC, off);
            dD += __shfl_xor(dD, off);
        }
        if (lane == 0) {
            cosc[(b0 + i + 0) * KC + k0] = dA * inv;
            cosc[(b0 + i + 1) * KC + k0] = dB * inv;
            cosc[(b0 + i + 2) * KC + k0] = dC * inv;
            cosc[(b0 + i + 3) * KC + k0] = dD * inv;
        }
    }
}

// ---------- wave argmax: ties -> smaller index (matches jax.lax.top_k) ----------
__device__ __forceinline__ void wave_argmax(float& bv, int& bi) {
    for (int off = 1; off < 64; off <<= 1) {
        float v2 = __shfl_xor(bv, off);
        int   i2 = __shfl_xor(bi, off);
        if (v2 > bv || (v2 == bv && i2 < bi)) { bv = v2; bi = i2; }
    }
}

// ---------- Kernel C: per-query top-NS clusters + inverted cluster->selector map ----------
__global__ void ktop_clusters(const float* __restrict__ cosc, int* __restrict__ cidx,
                              int* __restrict__ cnt, int* __restrict__ sel) {
    int b = blockIdx.x, t = threadIdx.x;
    int wave = t >> 6, lane = t & 63;
    __shared__ float vals[KC];
    __shared__ float wrv[4];
    __shared__ int   wri[4];
    for (int i = t; i < KC; i += 256) vals[i] = cosc[b * KC + i];
    __syncthreads();
    for (int s = 0; s < NS; ++s) {
        float bv = NEG_INF; int bi = 0x7fffffff;
        for (int i = t; i < KC; i += 256) {
            float v = vals[i];
            if (v > bv) { bv = v; bi = i; }
        }
        wave_argmax(bv, bi);
        if (lane == 0) { wrv[wave] = bv; wri[wave] = bi; }
        __syncthreads();
        if (t == 0) {
            float fv = wrv[0]; int fi = wri[0];
            for (int w = 1; w < 4; ++w) {
                float v2 = wrv[w]; int i2 = wri[w];
                if (v2 > fv || (v2 == fv && i2 < fi)) { fv = v2; fi = i2; }
            }
            cidx[b * NS + s] = fi;
            int pos = atomicAdd(&cnt[fi], 1);     // device-scope
            sel[fi * 64 + pos] = b * NS + s;
            vals[fi] = NEG_INF;
        }
        __syncthreads();
    }
}

// ---------- Kernel D: INSTRUMENTED 8x task-shifted repeat of the R3 body ----------
// Each block executes tasks (bid + r*500) % 4000, r=0..7. Every task is run by
// exactly 8 blocks; all writes are bit-identical (same inputs, same FP order)
// -> idempotent & deterministic. Purpose: make D's dispatch long enough to
// surface in the rocprof top-5 with real counters. D_var = (T - 143.1)/7.
__global__ void kcand(const float* __restrict__ qn, const float* __restrict__ data,
                      const int* __restrict__ cnt, const int* __restrict__ sel,
                      float* __restrict__ cosall) {
    int t = threadIdx.x;
    __shared__ int slist[64];
#pragma unroll 1
    for (int r = 0; r < 8; ++r) {
        int task = (blockIdx.x + r * 500) % (KC * 4);
        int c = task >> 2, sub = task & 3;
        int m = cnt[c];               // block-uniform -> barriers below are safe
        if (m == 0) continue;
        __syncthreads();              // prior repeat's slist readers done
        if (t < m) slist[t] = sel[c * 64 + t];
        __syncthreads();
        int wave = t >> 6, lane = t & 63;
        const float* base = data + (size_t)c * NPC * DIM;
        int n0 = sub * 64 + wave * 16;
        for (int it = 0; it < 4; ++it) {
            int n = n0 + it * 4;
            const float4* dpa = (const float4*)(base + (size_t)(n + 0) * DIM);
            const float4* dpb = (const float4*)(base + (size_t)(n + 1) * DIM);
            const float4* dpc = (const float4*)(base + (size_t)(n + 2) * DIM);
            const float4* dpd = (const float4*)(base + (size_t)(n + 3) * DIM);
            float4 a0 = dpa[lane], a1 = dpa[lane + 64], a2 = dpa[lane + 128];
            float4 e0 = dpb[lane], e1 = dpb[lane + 64], e2 = dpb[lane + 128];
            float4 f0 = dpc[lane], f1 = dpc[lane + 64], f2 = dpc[lane + 128];
            float4 g0 = dpd[lane], g1 = dpd[lane + 64], g2 = dpd[lane + 128];
            float sqA = 0.f, sqB = 0.f, sqC = 0.f, sqD = 0.f;
            DOT12(sqA, a0, a0); DOT12(sqA, a1, a1); DOT12(sqA, a2, a2);
            DOT12(sqB, e0, e0); DOT12(sqB, e1, e1); DOT12(sqB, e2, e2);
            DOT12(sqC, f0, f0); DOT12(sqC, f1, f1); DOT12(sqC, f2, f2);
            DOT12(sqD, g0, g0); DOT12(sqD, g1, g1); DOT12(sqD, g2, g2);
            for (int off = 1; off < 64; off <<= 1) {
                sqA += __shfl_xor(sqA, off); sqB += __shfl_xor(sqB, off);
                sqC += __shfl_xor(sqC, off); sqD += __shfl_xor(sqD, off);
            }
            float invA = 1.0f / fmaxf(sqrtf(sqA), 1e-12f);
            float invB = 1.0f / fmaxf(sqrtf(sqB), 1e-12f);
            float invC = 1.0f / fmaxf(sqrtf(sqC), 1e-12f);
            float invD = 1.0f / fmaxf(sqrtf(sqD), 1e-12f);
            for (int j = 0; j < m; ++j) {
                int i = slist[j];
                int b = i / NS;
                const float4* qp = (const float4*)(qn + (size_t)b * DIM);
                float4 q0 = qp[lane], q1 = qp[lane + 64], q2 = qp[lane + 128];
                float dA = 0.f, dB = 0.f, dC = 0.f, dD = 0.f;
                DOT12(dA, q0, a0); DOT12(dA, q1, a1); DOT12(dA, q2, a2);
                DOT12(dB, q0, e0); DOT12(dB, q1, e1); DOT12(dB, q2, e2);
                DOT12(dC, q0, f0); DOT12(dC, q1, f1); DOT12(dC, q2, f2);
                DOT12(dD, q0, g0); DOT12(dD, q1, g1); DOT12(dD, q2, g2);
                for (int off = 1; off < 64; off <<= 1) {
                    dA += __shfl_xor(dA, off); dB += __shfl_xor(dB, off);
                    dC += __shfl_xor(dC, off); dD += __shfl_xor(dD, off);
                }
                if (lane == 0) {
                    float* outp = cosall + (size_t)i * NPC + n;
                    outp[0] = dA * invA;
                    outp[1] = dB * invB;
                    outp[2] = dC * invC;
                    outp[3] = dD * invD;
                }
            }
        }
    }
}

// ---------- Kernel E: per-query top-K + id write + embedding gather ----------
__global__ void ktop_final(const float* __restrict__ cosall, const int* __restrict__ cidx,
                           const int* __restrict__ clusted, const float* __restrict__ data,
                           float* __restrict__ out) {
    int b = blockIdx.x, t = threadIdx.x;
    int wave = t >> 6, lane = t & 63;
    __shared__ float vals[NS * NPC];
    __shared__ float wrv[4];
    __shared__ int   wri[4];
    __shared__ int   docs[TOPK];
    for (int i = t; i < NS * NPC; i += 256) vals[i] = cosall[(size_t)b * (NS * NPC) + i];
    __syncthreads();
    for (int j = 0; j < TOPK; ++j) {
        float bv = NEG_INF; int bi = 0x7fffffff;
        for (int i = t; i < NS * NPC; i += 256) {
            float v = vals[i];
            if (v > bv) { bv = v; bi = i; }
        }
        wave_argmax(bv, bi);
        if (lane == 0) { wrv[wave] = bv; wri[wave] = bi; }
        __syncthreads();
        if (t == 0) {
            float fv = wrv[0]; int fi = wri[0];
            for (int w = 1; w < 4; ++w) {
                float v2 = wrv[w]; int i2 = wri[w];
                if (v2 > fv || (v2 == fv && i2 < fi)) { fv = v2; fi = i2; }
            }
            int s = fi >> 8, n = fi & (NPC - 1);
            int c = cidx[b * NS + s];
            int doc = c * NPC + n;
            docs[j] = doc;
            out[b * TOPK + j] = (float)clusted[doc];   // ids < 2^24, exact in f32
            vals[fi] = NEG_INF;
        }
        __syncthreads();
    }
    float* emb = out + BQ * TOPK;
    for (int idx = t; idx < TOPK * (DIM / 4); idx += 256) {
        int j = idx / (DIM / 4), col = idx - j * (DIM / 4);
        int doc = docs[j];
        ((float4*)(emb + ((size_t)(b * TOPK + j)) * DIM))[col] =
            ((const float4*)(data + (size_t)doc * DIM))[col];
    }
}

extern "C" void kernel_launch(void* const* d_in, const int* in_sizes, int n_in,
                              void* d_out, int out_size, void* d_ws, size_t ws_size,
                              hipStream_t stream) {
    const float* querys  = (const float*)d_in[0];   // (64, 768)
    const float* data    = (const float*)d_in[1];   // (1000, 256, 768)
    const float* centers = (const float*)d_in[2];   // (1000, 768)
    const int*   clusted = (const int*)d_in[3];     // (1000, 256)
    float* out = (float*)d_out;                     // [64*16 ids as float][64*16*768 emb]

    float* ws     = (float*)d_ws;
    float* qn     = ws;                              // 64*768
    float* cosc   = qn + BQ * DIM;                   // 64*1000
    int*   cidx   = (int*)(cosc + BQ * KC);          // 64*10
    float* cosall = (float*)(cidx + BQ * NS);        // 64*2560
    int*   cnt    = (int*)(cosall + BQ * NS * NPC);  // 1000
    int*   sel    = cnt + KC;                        // 1000*64

    knorm_q<<<BQ, 256, 0, stream>>>(querys, qn, cnt);
    kcenter_scores<<<KC, 256, 0, stream>>>(qn, centers, cosc);
    ktop_clusters<<<BQ, 256, 0, stream>>>(cosc, cidx, cnt, sel);
    kcand<<<KC * 4, 256, 0, stream>>>(qn, data, cnt, sel, cosall);
    ktop_final<<<BQ, 256, 0, stream>>>(cosall, cidx, clusted, data, out);
}

// Round 7
// 180.051 us; speedup vs baseline: 2.8417x; 2.8417x over previous
//
#include <hip/hip_runtime.h>
#include <math.h>

// Problem constants: B=64, K=1000, NPC=256, D=768, k=16, S=10
#define BQ   64
#define KC   1000
#define NPC  256
#define DIM  768
#define TOPK 16
#define NS   10

#define NEG_INF (-__builtin_inff())

#define DOT12(acc, A, Bv) \
    acc = fmaf(A.x, Bv.x, acc); acc = fmaf(A.y, Bv.y, acc); \
    acc = fmaf(A.z, Bv.z, acc); acc = fmaf(A.w, Bv.w, acc);

// NOTE: query normalization is dropped. score = dot(q_raw, x)/|x| = |q|*cos(q,x);
// per query row a uniform positive scale -> every top-k selection unchanged.
// Outputs (ids, raw embeddings) never expose the scores.

// ---------- Kernel B: cosc[b][k] = dot(q[b], centers[k]) / |centers[k]| ----------
// grid = 1000 blocks: (250 center-quads) x (4 query-groups of 16). One wave per center.
// Block i also zeroes cnt[i] (grid == KC).
__global__ void kcenter_scores(const float* __restrict__ q,
                               const float* __restrict__ centers,
                               float* __restrict__ cosc,
                               int* __restrict__ cnt) {
    if (threadIdx.x == 0) cnt[blockIdx.x] = 0;
    int wave = threadIdx.x >> 6, lane = threadIdx.x & 63;
    int cblk = blockIdx.x >> 2, qg = blockIdx.x & 3;
    int k0 = cblk * 4 + wave;                    // 250*4 = 1000 exactly
    const float4* cp = (const float4*)(centers + (size_t)k0 * DIM);
    float4 c0 = cp[lane], c1 = cp[lane + 64], c2 = cp[lane + 128];
    float sq = 0.f;
    DOT12(sq, c0, c0); DOT12(sq, c1, c1); DOT12(sq, c2, c2);
    for (int off = 1; off < 64; off <<= 1) sq += __shfl_xor(sq, off);
    float inv = 1.0f / fmaxf(sqrtf(sq), 1e-12f);
    int b0 = qg * 16;
    for (int i = 0; i < 16; i += 4) {
        const float4* qa = (const float4*)(q + (size_t)(b0 + i + 0) * DIM);
        const float4* qb = (const float4*)(q + (size_t)(b0 + i + 1) * DIM);
        const float4* qc = (const float4*)(q + (size_t)(b0 + i + 2) * DIM);
        const float4* qd = (const float4*)(q + (size_t)(b0 + i + 3) * DIM);
        float4 a0 = qa[lane], a1 = qa[lane + 64], a2 = qa[lane + 128];
        float4 e0 = qb[lane], e1 = qb[lane + 64], e2 = qb[lane + 128];
        float4 f0 = qc[lane], f1 = qc[lane + 64], f2 = qc[lane + 128];
        float4 g0 = qd[lane], g1 = qd[lane + 64], g2 = qd[lane + 128];
        float dA = 0.f, dB = 0.f, dC = 0.f, dD = 0.f;
        DOT12(dA, a0, c0); DOT12(dA, a1, c1); DOT12(dA, a2, c2);
        DOT12(dB, e0, c0); DOT12(dB, e1, c1); DOT12(dB, e2, c2);
        DOT12(dC, f0, c0); DOT12(dC, f1, c1); DOT12(dC, f2, c2);
        DOT12(dD, g0, c0); DOT12(dD, g1, c1); DOT12(dD, g2, c2);
        for (int off = 1; off < 64; off <<= 1) {
            dA += __shfl_xor(dA, off);
            dB += __shfl_xor(dB, off);
            dC += __shfl_xor(dC, off);
            dD += __shfl_xor(dD, off);
        }
        if (lane == 0) {
            cosc[(b0 + i + 0) * KC + k0] = dA * inv;
            cosc[(b0 + i + 1) * KC + k0] = dB * inv;
            cosc[(b0 + i + 2) * KC + k0] = dC * inv;
            cosc[(b0 + i + 3) * KC + k0] = dD * inv;
        }
    }
}

// ---------- wave argmax: ties -> smaller index (matches jax.lax.top_k) ----------
__device__ __forceinline__ void wave_argmax(float& bv, int& bi) {
    for (int off = 1; off < 64; off <<= 1) {
        float v2 = __shfl_xor(bv, off);
        int   i2 = __shfl_xor(bi, off);
        if (v2 > bv || (v2 == bv && i2 < bi)) { bv = v2; bi = i2; }
    }
}

// ---------- Kernel C: 1 wave per query; register-resident top-NS ----------
// grid = 64 blocks x 64 threads. Lane l holds cosc values at {l + 64j}.
__global__ void ktop_clusters(const float* __restrict__ cosc, int* __restrict__ cidx,
                              int* __restrict__ cnt, int* __restrict__ sel) {
    int b = blockIdx.x, l = threadIdx.x;
    const float* src = cosc + b * KC;
    float v[16];
#pragma unroll
    for (int j = 0; j < 16; ++j) {
        int i = l + 64 * j;
        v[j] = (i < KC) ? src[i] : NEG_INF;
    }
    for (int s = 0; s < NS; ++s) {
        float bv = v[0]; int bj = 0;
#pragma unroll
        for (int j = 1; j < 16; ++j)
            if (v[j] > bv) { bv = v[j]; bj = j; }     // strict > keeps smallest j
        int bi = l + 64 * bj;
        wave_argmax(bv, bi);
        int wl = bi & 63, wj = bi >> 6;
        if (l == wl) {
#pragma unroll
            for (int j = 0; j < 16; ++j) if (j == wj) v[j] = NEG_INF;
        }
        if (l == 0) {
            cidx[b * NS + s] = bi;
            int pos = atomicAdd(&cnt[bi], 1);         // set per cluster replay-invariant
            sel[bi * 64 + pos] = b * NS + s;
        }
    }
}

// ---------- Kernel D: 4-lane-per-doc candidate scores ----------
// grid = KC*4 blocks x 256 threads. Block (c,sub) owns docs sub*64..sub*64+63.
// Lane group of 4 owns one doc: lane accumulates 192 dims in-register (48
// independent float4 loads to pipeline), then a TWO-step shuffle reduce.
#define MAXM 8
__global__ __launch_bounds__(256) void kcand(const float* __restrict__ q,
                                             const float* __restrict__ data,
                                             const int* __restrict__ cnt,
                                             const int* __restrict__ sel,
                                             float* __restrict__ cosall) {
    int c = blockIdx.x >> 2, sub = blockIdx.x & 3;
    int m = cnt[c];
    if (m == 0) return;
    int t = threadIdx.x;
    __shared__ int slist[64];
    if (t < m) slist[t] = sel[c * 64 + t];
    __syncthreads();
    int wave = t >> 6, l = t & 63;
    int g = l >> 2, p = l & 3;                       // doc-group, slot in group
    int n = sub * 64 + wave * 16 + g;                // doc index in cluster
    const float4* drow = (const float4*)(data + ((size_t)c * NPC + n) * DIM);
    const float4* q4 = (const float4*)q;
    for (int j0 = 0; j0 < m; j0 += MAXM) {
        int mm = min(m - j0, MAXM);
        int qr[MAXM];
#pragma unroll
        for (int jj = 0; jj < MAXM; ++jj) {
            int si = slist[(jj < mm) ? (j0 + jj) : j0];
            qr[jj] = si / NS;
        }
        float acc[MAXM];
#pragma unroll
        for (int jj = 0; jj < MAXM; ++jj) acc[jj] = 0.f;
        float sq = 0.f;
#pragma unroll 4
        for (int cc = 0; cc < 48; ++cc) {
            float4 dv = drow[p + 4 * cc];
            DOT12(sq, dv, dv);
#pragma unroll
            for (int jj = 0; jj < MAXM; ++jj) {
                if (jj < mm) {
                    float4 qv = q4[(size_t)qr[jj] * (DIM / 4) + p + 4 * cc];
                    DOT12(acc[jj], dv, qv);
                }
            }
        }
        // 4-lane reduce: two steps only
        sq += __shfl_xor(sq, 1); sq += __shfl_xor(sq, 2);
#pragma unroll
        for (int jj = 0; jj < MAXM; ++jj) {
            acc[jj] += __shfl_xor(acc[jj], 1);
            acc[jj] += __shfl_xor(acc[jj], 2);
        }
        float invd = 1.0f / fmaxf(sqrtf(sq), 1e-12f);
        if (p == 0) {
#pragma unroll
            for (int jj = 0; jj < MAXM; ++jj) {
                if (jj < mm) {
                    int i = slist[j0 + jj];
                    cosall[(size_t)i * NPC + n] = acc[jj] * invd;
                }
            }
        }
    }
}

// ---------- Kernel E: 1 wave per query; register-resident top-K + gather ----------
// grid = 64 blocks x 64 threads. 2560 = 64 lanes x 40 values.
__global__ void ktop_final(const float* __restrict__ cosall, const int* __restrict__ cidx,
                           const int* __restrict__ clusted, const float* __restrict__ data,
                           float* __restrict__ out) {
    int b = blockIdx.x, l = threadIdx.x;
    const float* src = cosall + (size_t)b * (NS * NPC);
    float v[40];
#pragma unroll
    for (int j = 0; j < 40; ++j) v[j] = src[l + 64 * j];
    __shared__ int docs[TOPK];
    for (int s = 0; s < TOPK; ++s) {
        float bv = v[0]; int bj = 0;
#pragma unroll
        for (int j = 1; j < 40; ++j)
            if (v[j] > bv) { bv = v[j]; bj = j; }     // strict > keeps smallest j
        int bi = l + 64 * bj;
        wave_argmax(bv, bi);
        int wl = bi & 63, wj = bi >> 6;
        if (l == wl) {
#pragma unroll
            for (int j = 0; j < 40; ++j) if (j == wj) v[j] = NEG_INF;
        }
        int ss = bi >> 8, nn = bi & (NPC - 1);
        int cc = cidx[b * NS + ss];                   // uniform load (all lanes)
        int doc = cc * NPC + nn;
        if (l == 0) {
            docs[s] = doc;
            out[b * TOPK + s] = (float)clusted[doc];  // ids < 2^24, exact in f32
        }
    }
    __syncthreads();
    float* emb = out + BQ * TOPK;
    for (int j = 0; j < TOPK; ++j) {
        int doc = docs[j];
        const float4* s4 = (const float4*)(data + (size_t)doc * DIM);
        float4* d4 = (float4*)(emb + (size_t)(b * TOPK + j) * DIM);
        for (int col = l; col < DIM / 4; col += 64) d4[col] = s4[col];
    }
}

extern "C" void kernel_launch(void* const* d_in, const int* in_sizes, int n_in,
                              void* d_out, int out_size, void* d_ws, size_t ws_size,
                              hipStream_t stream) {
    const float* querys  = (const float*)d_in[0];   // (64, 768)
    const float* data    = (const float*)d_in[1];   // (1000, 256, 768)
    const float* centers = (const float*)d_in[2];   // (1000, 768)
    const int*   clusted = (const int*)d_in[3];     // (1000, 256)
    float* out = (float*)d_out;                     // [64*16 ids as float][64*16*768 emb]

    float* ws     = (float*)d_ws;
    float* cosc   = ws;                              // 64*1000
    int*   cidx   = (int*)(cosc + BQ * KC);          // 64*10
    float* cosall = (float*)(cidx + BQ * NS);        // 64*2560
    int*   cnt    = (int*)(cosall + BQ * NS * NPC);  // 1000
    int*   sel    = cnt + KC;                        // 1000*64

    kcenter_scores<<<KC, 256, 0, stream>>>(querys, centers, cosc, cnt);
    ktop_clusters<<<BQ, 64, 0, stream>>>(cosc, cidx, cnt, sel);
    kcand<<<KC * 4, 256, 0, stream>>>(querys, data, cnt, sel, cosall);
    ktop_final<<<BQ, 64, 0, stream>>>(cosall, cidx, clusted, data, out);
}

// Round 8
// 143.176 us; speedup vs baseline: 3.5736x; 1.2575x over previous
//
#include <hip/hip_runtime.h>
#include <math.h>

// Problem constants: B=64, K=1000, NPC=256, D=768, k=16, S=10
#define BQ   64
#define KC   1000
#define NPC  256
#define DIM  768
#define TOPK 16
#define NS   10

#define NEG_INF (-__builtin_inff())

#define DOT12(acc, A, Bv) \
    acc = fmaf(A.x, Bv.x, acc); acc = fmaf(A.y, Bv.y, acc); \
    acc = fmaf(A.z, Bv.z, acc); acc = fmaf(A.w, Bv.w, acc);

// ---------- Kernel A: normalize queries -> qn ; blocks 0..3 also zero cnt[] ----------
__global__ void knorm_q(const float* __restrict__ q, float* __restrict__ qn,
                        int* __restrict__ cnt) {
    int b = blockIdx.x, t = threadIdx.x;
    if (b < 4 && t < 250) cnt[b * 250 + t] = 0;
    const float* row = q + b * DIM;
    float v0 = row[t], v1 = row[t + 256], v2 = row[t + 512];
    __shared__ float red[256];
    red[t] = v0 * v0 + v1 * v1 + v2 * v2;
    __syncthreads();
    for (int off = 128; off; off >>= 1) {
        if (t < off) red[t] += red[t + off];
        __syncthreads();
    }
    float scale = 1.0f / fmaxf(sqrtf(red[0]), 1e-12f);
    qn[b * DIM + t]       = v0 * scale;
    qn[b * DIM + t + 256] = v1 * scale;
    qn[b * DIM + t + 512] = v2 * scale;
}

// ---------- Kernel B: cos_c[b][k] = dot(qn[b], centers[k]) / |centers[k]| ----------
__global__ void kcenter_scores(const float* __restrict__ qn,
                               const float* __restrict__ centers,
                               float* __restrict__ cosc) {
    int wave = threadIdx.x >> 6, lane = threadIdx.x & 63;
    int cblk = blockIdx.x >> 2, qg = blockIdx.x & 3;
    int k0 = cblk * 4 + wave;                    // 250*4 = 1000 exactly
    const float4* cp = (const float4*)(centers + (size_t)k0 * DIM);
    float4 c0 = cp[lane], c1 = cp[lane + 64], c2 = cp[lane + 128];
    float sq = 0.f;
    DOT12(sq, c0, c0); DOT12(sq, c1, c1); DOT12(sq, c2, c2);
    for (int off = 1; off < 64; off <<= 1) sq += __shfl_xor(sq, off);
    float inv = 1.0f / fmaxf(sqrtf(sq), 1e-12f);
    int b0 = qg * 16;
    for (int i = 0; i < 16; i += 4) {
        const float4* qa = (const float4*)(qn + (size_t)(b0 + i + 0) * DIM);
        const float4* qb = (const float4*)(qn + (size_t)(b0 + i + 1) * DIM);
        const float4* qc = (const float4*)(qn + (size_t)(b0 + i + 2) * DIM);
        const float4* qd = (const float4*)(qn + (size_t)(b0 + i + 3) * DIM);
        float4 a0 = qa[lane], a1 = qa[lane + 64], a2 = qa[lane + 128];
        float4 e0 = qb[lane], e1 = qb[lane + 64], e2 = qb[lane + 128];
        float4 f0 = qc[lane], f1 = qc[lane + 64], f2 = qc[lane + 128];
        float4 g0 = qd[lane], g1 = qd[lane + 64], g2 = qd[lane + 128];
        float dA = 0.f, dB = 0.f, dC = 0.f, dD = 0.f;
        DOT12(dA, a0, c0); DOT12(dA, a1, c1); DOT12(dA, a2, c2);
        DOT12(dB, e0, c0); DOT12(dB, e1, c1); DOT12(dB, e2, c2);
        DOT12(dC, f0, c0); DOT12(dC, f1, c1); DOT12(dC, f2, c2);
        DOT12(dD, g0, c0); DOT12(dD, g1, c1); DOT12(dD, g2, c2);
        for (int off = 1; off < 64; off <<= 1) {
            dA += __shfl_xor(dA, off);
            dB += __shfl_xor(dB, off);
            dC += __shfl_xor(dC, off);
            dD += __shfl_xor(dD, off);
        }
        if (lane == 0) {
            cosc[(b0 + i + 0) * KC + k0] = dA * inv;
            cosc[(b0 + i + 1) * KC + k0] = dB * inv;
            cosc[(b0 + i + 2) * KC + k0] = dC * inv;
            cosc[(b0 + i + 3) * KC + k0] = dD * inv;
        }
    }
}

// ---------- wave argmax: ties -> smaller index (matches jax.lax.top_k) ----------
__device__ __forceinline__ void wave_argmax(float& bv, int& bi) {
    for (int off = 1; off < 64; off <<= 1) {
        float v2 = __shfl_xor(bv, off);
        int   i2 = __shfl_xor(bi, off);
        if (v2 > bv || (v2 == bv && i2 < bi)) { bv = v2; bi = i2; }
    }
}

// ---------- Kernel C: per-query top-NS clusters + inverted cluster->selector map ----------
__global__ void ktop_clusters(const float* __restrict__ cosc, int* __restrict__ cidx,
                              int* __restrict__ cnt, int* __restrict__ sel) {
    int b = blockIdx.x, t = threadIdx.x;
    int wave = t >> 6, lane = t & 63;
    __shared__ float vals[KC];
    __shared__ float wrv[4];
    __shared__ int   wri[4];
    for (int i = t; i < KC; i += 256) vals[i] = cosc[b * KC + i];
    __syncthreads();
    for (int s = 0; s < NS; ++s) {
        float bv = NEG_INF; int bi = 0x7fffffff;
        for (int i = t; i < KC; i += 256) {
            float v = vals[i];
            if (v > bv) { bv = v; bi = i; }
        }
        wave_argmax(bv, bi);
        if (lane == 0) { wrv[wave] = bv; wri[wave] = bi; }
        __syncthreads();
        if (t == 0) {
            float fv = wrv[0]; int fi = wri[0];
            for (int w = 1; w < 4; ++w) {
                float v2 = wrv[w]; int i2 = wri[w];
                if (v2 > fv || (v2 == fv && i2 < fi)) { fv = v2; fi = i2; }
            }
            cidx[b * NS + s] = fi;
            int pos = atomicAdd(&cnt[fi], 1);     // device-scope
            sel[fi * 64 + pos] = b * NS + s;
            vals[fi] = NEG_INF;
        }
        __syncthreads();
    }
}

// ---------- Kernel D: software-pipelined candidate cosines ----------
// Structure identical to R3 (contiguous 1KB wave loads, 4 docs/step) but with
// an explicit 2-deep register ping-pong so >=12 loads stay in flight through
// every shuffle-reduction phase. FP order per output identical to R3.

#define LOADB(buf, itv) do {                                                   \
    int nb_ = n0 + (itv) * 4;                                                  \
    const float4* dp0_ = (const float4*)(base + (size_t)(nb_ + 0) * DIM);      \
    const float4* dp1_ = (const float4*)(base + (size_t)(nb_ + 1) * DIM);      \
    const float4* dp2_ = (const float4*)(base + (size_t)(nb_ + 2) * DIM);      \
    const float4* dp3_ = (const float4*)(base + (size_t)(nb_ + 3) * DIM);      \
    buf[0] = dp0_[lane]; buf[1]  = dp0_[lane + 64]; buf[2]  = dp0_[lane + 128];\
    buf[3] = dp1_[lane]; buf[4]  = dp1_[lane + 64]; buf[5]  = dp1_[lane + 128];\
    buf[6] = dp2_[lane]; buf[7]  = dp2_[lane + 64]; buf[8]  = dp2_[lane + 128];\
    buf[9] = dp3_[lane]; buf[10] = dp3_[lane + 64]; buf[11] = dp3_[lane + 128];\
} while (0)

#define PROCB(buf, itv) do {                                                   \
    int nb_ = n0 + (itv) * 4;                                                  \
    float s0 = 0.f, s1 = 0.f, s2 = 0.f, s3 = 0.f;                              \
    DOT12(s0, buf[0], buf[0]); DOT12(s0, buf[1], buf[1]); DOT12(s0, buf[2], buf[2]); \
    DOT12(s1, buf[3], buf[3]); DOT12(s1, buf[4], buf[4]); DOT12(s1, buf[5], buf[5]); \
    DOT12(s2, buf[6], buf[6]); DOT12(s2, buf[7], buf[7]); DOT12(s2, buf[8], buf[8]); \
    DOT12(s3, buf[9], buf[9]); DOT12(s3, buf[10], buf[10]); DOT12(s3, buf[11], buf[11]); \
    for (int off = 1; off < 64; off <<= 1) {                                   \
        s0 += __shfl_xor(s0, off); s1 += __shfl_xor(s1, off);                  \
        s2 += __shfl_xor(s2, off); s3 += __shfl_xor(s3, off);                  \
    }                                                                          \
    float i0 = 1.0f / fmaxf(sqrtf(s0), 1e-12f);                                \
    float i1 = 1.0f / fmaxf(sqrtf(s1), 1e-12f);                                \
    float i2 = 1.0f / fmaxf(sqrtf(s2), 1e-12f);                                \
    float i3 = 1.0f / fmaxf(sqrtf(s3), 1e-12f);                                \
    for (int j = 0; j < m; ++j) {                                              \
        int sidx_ = slist[j];                                                  \
        int brow_ = sidx_ / NS;                                                \
        const float4* qp_ = (const float4*)(qn + (size_t)brow_ * DIM);         \
        float4 q0 = qp_[lane], q1 = qp_[lane + 64], q2 = qp_[lane + 128];      \
        float d0 = 0.f, d1 = 0.f, d2 = 0.f, d3 = 0.f;                          \
        DOT12(d0, q0, buf[0]); DOT12(d0, q1, buf[1]); DOT12(d0, q2, buf[2]);   \
        DOT12(d1, q0, buf[3]); DOT12(d1, q1, buf[4]); DOT12(d1, q2, buf[5]);   \
        DOT12(d2, q0, buf[6]); DOT12(d2, q1, buf[7]); DOT12(d2, q2, buf[8]);   \
        DOT12(d3, q0, buf[9]); DOT12(d3, q1, buf[10]); DOT12(d3, q2, buf[11]); \
        for (int off = 1; off < 64; off <<= 1) {                               \
            d0 += __shfl_xor(d0, off); d1 += __shfl_xor(d1, off);              \
            d2 += __shfl_xor(d2, off); d3 += __shfl_xor(d3, off);              \
        }                                                                      \
        if (lane == 0) {                                                       \
            float* outp_ = cosall + (size_t)sidx_ * NPC + nb_;                 \
            outp_[0] = d0 * i0; outp_[1] = d1 * i1;                            \
            outp_[2] = d2 * i2; outp_[3] = d3 * i3;                            \
        }                                                                      \
    }                                                                          \
} while (0)

__global__ __launch_bounds__(256) void kcand(const float* __restrict__ qn,
                                             const float* __restrict__ data,
                                             const int* __restrict__ cnt,
                                             const int* __restrict__ sel,
                                             float* __restrict__ cosall) {
    int c = blockIdx.x >> 2, sub = blockIdx.x & 3;
    int m = cnt[c];
    if (m == 0) return;
    int t = threadIdx.x;
    __shared__ int slist[64];
    if (t < m) slist[t] = sel[c * 64 + t];
    __syncthreads();
    int wave = t >> 6, lane = t & 63;
    const float* base = data + (size_t)c * NPC * DIM;
    int n0 = sub * 64 + wave * 16;

    float4 bufA[12], bufB[12];
    LOADB(bufA, 0);
    LOADB(bufB, 1);     // 24 loads in flight
    PROCB(bufA, 0);     // bufB still flying during reductions
    LOADB(bufA, 2);
    PROCB(bufB, 1);
    LOADB(bufB, 3);
    PROCB(bufA, 2);
    PROCB(bufB, 3);
}

// ---------- Kernel E: per-query top-K + id write + embedding gather ----------
__global__ void ktop_final(const float* __restrict__ cosall, const int* __restrict__ cidx,
                           const int* __restrict__ clusted, const float* __restrict__ data,
                           float* __restrict__ out) {
    int b = blockIdx.x, t = threadIdx.x;
    int wave = t >> 6, lane = t & 63;
    __shared__ float vals[NS * NPC];
    __shared__ float wrv[4];
    __shared__ int   wri[4];
    __shared__ int   docs[TOPK];
    for (int i = t; i < NS * NPC; i += 256) vals[i] = cosall[(size_t)b * (NS * NPC) + i];
    __syncthreads();
    for (int j = 0; j < TOPK; ++j) {
        float bv = NEG_INF; int bi = 0x7fffffff;
        for (int i = t; i < NS * NPC; i += 256) {
            float v = vals[i];
            if (v > bv) { bv = v; bi = i; }
        }
        wave_argmax(bv, bi);
        if (lane == 0) { wrv[wave] = bv; wri[wave] = bi; }
        __syncthreads();
        if (t == 0) {
            float fv = wrv[0]; int fi = wri[0];
            for (int w = 1; w < 4; ++w) {
                float v2 = wrv[w]; int i2 = wri[w];
                if (v2 > fv || (v2 == fv && i2 < fi)) { fv = v2; fi = i2; }
            }
            int s = fi >> 8, n = fi & (NPC - 1);
            int c = cidx[b * NS + s];
            int doc = c * NPC + n;
            docs[j] = doc;
            out[b * TOPK + j] = (float)clusted[doc];   // ids < 2^24, exact in f32
            vals[fi] = NEG_INF;
        }
        __syncthreads();
    }
    float* emb = out + BQ * TOPK;
    for (int idx = t; idx < TOPK * (DIM / 4); idx += 256) {
        int j = idx / (DIM / 4), col = idx - j * (DIM / 4);
        int doc = docs[j];
        ((float4*)(emb + ((size_t)(b * TOPK + j)) * DIM))[col] =
            ((const float4*)(data + (size_t)doc * DIM))[col];
    }
}

extern "C" void kernel_launch(void* const* d_in, const int* in_sizes, int n_in,
                              void* d_out, int out_size, void* d_ws, size_t ws_size,
                              hipStream_t stream) {
    const float* querys  = (const float*)d_in[0];   // (64, 768)
    const float* data    = (const float*)d_in[1];   // (1000, 256, 768)
    const float* centers = (const float*)d_in[2];   // (1000, 768)
    const int*   clusted = (const int*)d_in[3];     // (1000, 256)
    float* out = (float*)d_out;                     // [64*16 ids as float][64*16*768 emb]

    float* ws     = (float*)d_ws;
    float* qn     = ws;                              // 64*768
    float* cosc   = qn + BQ * DIM;                   // 64*1000
    int*   cidx   = (int*)(cosc + BQ * KC);          // 64*10
    float* cosall = (float*)(cidx + BQ * NS);        // 64*2560
    int*   cnt    = (int*)(cosall + BQ * NS * NPC);  // 1000
    int*   sel    = cnt + KC;                        // 1000*64

    knorm_q<<<BQ, 256, 0, stream>>>(querys, qn, cnt);
    kcenter_scores<<<KC, 256, 0, stream>>>(qn, centers, cosc);
    ktop_clusters<<<BQ, 256, 0, stream>>>(cosc, cidx, cnt, sel);
    kcand<<<KC * 4, 256, 0, stream>>>(qn, data, cnt, sel, cosall);
    ktop_final<<<BQ, 256, 0, stream>>>(cosall, cidx, clusted, data, out);
}

// Round 9
// 138.123 us; speedup vs baseline: 3.7043x; 1.0366x over previous
//
#include <hip/hip_runtime.h>
#include <math.h>

// Problem constants: B=64, K=1000, NPC=256, D=768, k=16, S=10
#define BQ   64
#define KC   1000
#define NPC  256
#define DIM  768
#define TOPK 16
#define NS   10

#define NEG_INF (-__builtin_inff())

#define DOT12(acc, A, Bv) \
    acc = fmaf(A.x, Bv.x, acc); acc = fmaf(A.y, Bv.y, acc); \
    acc = fmaf(A.z, Bv.z, acc); acc = fmaf(A.w, Bv.w, acc);

// ---------- Kernel A: normalize queries -> qn ; blocks 0..3 also zero cnt[] ----------
__global__ void knorm_q(const float* __restrict__ q, float* __restrict__ qn,
                        int* __restrict__ cnt) {
    int b = blockIdx.x, t = threadIdx.x;
    if (b < 4 && t < 250) cnt[b * 250 + t] = 0;
    const float* row = q + b * DIM;
    float v0 = row[t], v1 = row[t + 256], v2 = row[t + 512];
    __shared__ float red[256];
    red[t] = v0 * v0 + v1 * v1 + v2 * v2;
    __syncthreads();
    for (int off = 128; off; off >>= 1) {
        if (t < off) red[t] += red[t + off];
        __syncthreads();
    }
    float scale = 1.0f / fmaxf(sqrtf(red[0]), 1e-12f);
    qn[b * DIM + t]       = v0 * scale;
    qn[b * DIM + t + 256] = v1 * scale;
    qn[b * DIM + t + 512] = v2 * scale;
}

// ---------- Kernel B: cos_c[b][k] = dot(qn[b], centers[k]) / |centers[k]| ----------
__global__ void kcenter_scores(const float* __restrict__ qn,
                               const float* __restrict__ centers,
                               float* __restrict__ cosc) {
    int wave = threadIdx.x >> 6, lane = threadIdx.x & 63;
    int cblk = blockIdx.x >> 2, qg = blockIdx.x & 3;
    int k0 = cblk * 4 + wave;                    // 250*4 = 1000 exactly
    const float4* cp = (const float4*)(centers + (size_t)k0 * DIM);
    float4 c0 = cp[lane], c1 = cp[lane + 64], c2 = cp[lane + 128];
    float sq = 0.f;
    DOT12(sq, c0, c0); DOT12(sq, c1, c1); DOT12(sq, c2, c2);
    for (int off = 1; off < 64; off <<= 1) sq += __shfl_xor(sq, off);
    float inv = 1.0f / fmaxf(sqrtf(sq), 1e-12f);
    int b0 = qg * 16;
    for (int i = 0; i < 16; i += 4) {
        const float4* qa = (const float4*)(qn + (size_t)(b0 + i + 0) * DIM);
        const float4* qb = (const float4*)(qn + (size_t)(b0 + i + 1) * DIM);
        const float4* qc = (const float4*)(qn + (size_t)(b0 + i + 2) * DIM);
        const float4* qd = (const float4*)(qn + (size_t)(b0 + i + 3) * DIM);
        float4 a0 = qa[lane], a1 = qa[lane + 64], a2 = qa[lane + 128];
        float4 e0 = qb[lane], e1 = qb[lane + 64], e2 = qb[lane + 128];
        float4 f0 = qc[lane], f1 = qc[lane + 64], f2 = qc[lane + 128];
        float4 g0 = qd[lane], g1 = qd[lane + 64], g2 = qd[lane + 128];
        float dA = 0.f, dB = 0.f, dC = 0.f, dD = 0.f;
        DOT12(dA, a0, c0); DOT12(dA, a1, c1); DOT12(dA, a2, c2);
        DOT12(dB, e0, c0); DOT12(dB, e1, c1); DOT12(dB, e2, c2);
        DOT12(dC, f0, c0); DOT12(dC, f1, c1); DOT12(dC, f2, c2);
        DOT12(dD, g0, c0); DOT12(dD, g1, c1); DOT12(dD, g2, c2);
        for (int off = 1; off < 64; off <<= 1) {
            dA += __shfl_xor(dA, off);
            dB += __shfl_xor(dB, off);
            dC += __shfl_xor(dC, off);
            dD += __shfl_xor(dD, off);
        }
        if (lane == 0) {
            cosc[(b0 + i + 0) * KC + k0] = dA * inv;
            cosc[(b0 + i + 1) * KC + k0] = dB * inv;
            cosc[(b0 + i + 2) * KC + k0] = dC * inv;
            cosc[(b0 + i + 3) * KC + k0] = dD * inv;
        }
    }
}

// ---------- wave argmax: ties -> smaller index (matches jax.lax.top_k) ----------
__device__ __forceinline__ void wave_argmax(float& bv, int& bi) {
    for (int off = 1; off < 64; off <<= 1) {
        float v2 = __shfl_xor(bv, off);
        int   i2 = __shfl_xor(bi, off);
        if (v2 > bv || (v2 == bv && i2 < bi)) { bv = v2; bi = i2; }
    }
}

// ---------- Kernel C: per-query top-NS clusters + inverted cluster->selector map ----------
__global__ void ktop_clusters(const float* __restrict__ cosc, int* __restrict__ cidx,
                              int* __restrict__ cnt, int* __restrict__ sel) {
    int b = blockIdx.x, t = threadIdx.x;
    int wave = t >> 6, lane = t & 63;
    __shared__ float vals[KC];
    __shared__ float wrv[4];
    __shared__ int   wri[4];
    for (int i = t; i < KC; i += 256) vals[i] = cosc[b * KC + i];
    __syncthreads();
    for (int s = 0; s < NS; ++s) {
        float bv = NEG_INF; int bi = 0x7fffffff;
        for (int i = t; i < KC; i += 256) {
            float v = vals[i];
            if (v > bv) { bv = v; bi = i; }
        }
        wave_argmax(bv, bi);
        if (lane == 0) { wrv[wave] = bv; wri[wave] = bi; }
        __syncthreads();
        if (t == 0) {
            float fv = wrv[0]; int fi = wri[0];
            for (int w = 1; w < 4; ++w) {
                float v2 = wrv[w]; int i2 = wri[w];
                if (v2 > fv || (v2 == fv && i2 < fi)) { fv = v2; fi = i2; }
            }
            cidx[b * NS + s] = fi;
            int pos = atomicAdd(&cnt[fi], 1);     // device-scope
            sel[fi * 64 + pos] = b * NS + s;
            vals[fi] = NEG_INF;
        }
        __syncthreads();
    }
}

// ---------- Kernel D: vmcnt-clean software-pipelined candidate cosines ----------
// Key fix vs R8: the compute phase is VMEM-FREE (q rows read from LDS via
// ds_read; results buffered to LDS via ds_write). The only vmem ops in the
// pipelined region are the 12-load doc prefetches, so the compiler can emit
// counted s_waitcnt vmcnt(12) and the ping-pong buffer stays in flight
// through every shuffle-reduction. FP math per output identical to R3.
#define QROWS 15

#define LOADB(buf, itv) do {                                                   \
    int nb_ = n0 + (itv) * 4;                                                  \
    const float4* dp0_ = (const float4*)(base + (size_t)(nb_ + 0) * DIM);      \
    const float4* dp1_ = (const float4*)(base + (size_t)(nb_ + 1) * DIM);      \
    const float4* dp2_ = (const float4*)(base + (size_t)(nb_ + 2) * DIM);      \
    const float4* dp3_ = (const float4*)(base + (size_t)(nb_ + 3) * DIM);      \
    buf[0] = dp0_[lane]; buf[1]  = dp0_[lane + 64]; buf[2]  = dp0_[lane + 128];\
    buf[3] = dp1_[lane]; buf[4]  = dp1_[lane + 64]; buf[5]  = dp1_[lane + 128];\
    buf[6] = dp2_[lane]; buf[7]  = dp2_[lane + 64]; buf[8]  = dp2_[lane + 128];\
    buf[9] = dp3_[lane]; buf[10] = dp3_[lane + 64]; buf[11] = dp3_[lane + 128];\
} while (0)

#define PROCB(buf, itv) do {                                                   \
    float s0 = 0.f, s1 = 0.f, s2 = 0.f, s3 = 0.f;                              \
    DOT12(s0, buf[0], buf[0]); DOT12(s0, buf[1], buf[1]); DOT12(s0, buf[2], buf[2]); \
    DOT12(s1, buf[3], buf[3]); DOT12(s1, buf[4], buf[4]); DOT12(s1, buf[5], buf[5]); \
    DOT12(s2, buf[6], buf[6]); DOT12(s2, buf[7], buf[7]); DOT12(s2, buf[8], buf[8]); \
    DOT12(s3, buf[9], buf[9]); DOT12(s3, buf[10], buf[10]); DOT12(s3, buf[11], buf[11]); \
    for (int off = 1; off < 64; off <<= 1) {                                   \
        s0 += __shfl_xor(s0, off); s1 += __shfl_xor(s1, off);                  \
        s2 += __shfl_xor(s2, off); s3 += __shfl_xor(s3, off);                  \
    }                                                                          \
    float i0 = 1.0f / fmaxf(sqrtf(s0), 1e-12f);                                \
    float i1 = 1.0f / fmaxf(sqrtf(s1), 1e-12f);                                \
    float i2 = 1.0f / fmaxf(sqrtf(s2), 1e-12f);                                \
    float i3 = 1.0f / fmaxf(sqrtf(s3), 1e-12f);                                \
    for (int j = 0; j < mq; ++j) {                                             \
        float4 q0 = *(const float4*)&qlds[j * DIM + lane * 4];                 \
        float4 q1 = *(const float4*)&qlds[j * DIM + (lane + 64) * 4];          \
        float4 q2 = *(const float4*)&qlds[j * DIM + (lane + 128) * 4];         \
        float d0 = 0.f, d1 = 0.f, d2 = 0.f, d3 = 0.f;                          \
        DOT12(d0, q0, buf[0]); DOT12(d0, q1, buf[1]); DOT12(d0, q2, buf[2]);   \
        DOT12(d1, q0, buf[3]); DOT12(d1, q1, buf[4]); DOT12(d1, q2, buf[5]);   \
        DOT12(d2, q0, buf[6]); DOT12(d2, q1, buf[7]); DOT12(d2, q2, buf[8]);   \
        DOT12(d3, q0, buf[9]); DOT12(d3, q1, buf[10]); DOT12(d3, q2, buf[11]); \
        for (int off = 1; off < 64; off <<= 1) {                               \
            d0 += __shfl_xor(d0, off); d1 += __shfl_xor(d1, off);              \
            d2 += __shfl_xor(d2, off); d3 += __shfl_xor(d3, off);              \
        }                                                                      \
        if (lane == 0) {                                                       \
            res[wave][j][(itv) * 4 + 0] = d0 * i0;                             \
            res[wave][j][(itv) * 4 + 1] = d1 * i1;                             \
            res[wave][j][(itv) * 4 + 2] = d2 * i2;                             \
            res[wave][j][(itv) * 4 + 3] = d3 * i3;                             \
        }                                                                      \
    }                                                                          \
} while (0)

__global__ __launch_bounds__(256, 3) void kcand(const float* __restrict__ qn,
                                                const float* __restrict__ data,
                                                const int* __restrict__ cnt,
                                                const int* __restrict__ sel,
                                                float* __restrict__ cosall) {
    int c = blockIdx.x >> 2, sub = blockIdx.x & 3;
    int m = cnt[c];
    if (m == 0) return;
    int t = threadIdx.x;
    __shared__ int   slist[64];
    __shared__ float qlds[QROWS * DIM];          // 45 KB
    __shared__ float res[4][QROWS][16];          // 3.75 KB
    if (t < m) slist[t] = sel[c * 64 + t];
    __syncthreads();
    int mq = min(m, QROWS);
    for (int j = 0; j < mq; ++j) {
        int brow = slist[j] / NS;
        const float4* src = (const float4*)(qn + (size_t)brow * DIM);
        float4* dst = (float4*)&qlds[j * DIM];
        for (int idx = t; idx < DIM / 4; idx += 256) dst[idx] = src[idx];
    }
    __syncthreads();   // clean vmcnt slate before the pipelined region
    int wave = t >> 6, lane = t & 63;
    const float* base = data + (size_t)c * NPC * DIM;
    int n0 = sub * 64 + wave * 16;

    float4 bufA[12], bufB[12];
    LOADB(bufA, 0);
    LOADB(bufB, 1);     // 24 loads in flight
    PROCB(bufA, 0);     // vmem-free: bufB stays in flight
    LOADB(bufA, 2);
    PROCB(bufB, 1);
    LOADB(bufB, 3);
    PROCB(bufA, 2);
    PROCB(bufB, 3);

    // flush buffered results (coalesced 64B segments)
    for (int idx = lane; idx < mq * 16; idx += 64) {
        int j = idx >> 4, nn = idx & 15;
        cosall[(size_t)slist[j] * NPC + n0 + nn] = res[wave][j][nn];
    }

    // rare epilogue: selectors beyond QROWS (recompute from L2-warm data)
    for (int j = QROWS; j < m; ++j) {
        int sidx = slist[j];
        int brow = sidx / NS;
        const float4* qp = (const float4*)(qn + (size_t)brow * DIM);
        float4 q0 = qp[lane], q1 = qp[lane + 64], q2 = qp[lane + 128];
        for (int it = 0; it < 4; ++it) {
            int n = n0 + it * 4;
            const float4* dp0 = (const float4*)(base + (size_t)(n + 0) * DIM);
            const float4* dp1 = (const float4*)(base + (size_t)(n + 1) * DIM);
            const float4* dp2 = (const float4*)(base + (size_t)(n + 2) * DIM);
            const float4* dp3 = (const float4*)(base + (size_t)(n + 3) * DIM);
            float4 a0 = dp0[lane], a1 = dp0[lane + 64], a2 = dp0[lane + 128];
            float4 e0 = dp1[lane], e1 = dp1[lane + 64], e2 = dp1[lane + 128];
            float4 f0 = dp2[lane], f1 = dp2[lane + 64], f2 = dp2[lane + 128];
            float4 g0 = dp3[lane], g1 = dp3[lane + 64], g2 = dp3[lane + 128];
            float s0 = 0.f, s1 = 0.f, s2 = 0.f, s3 = 0.f;
            DOT12(s0, a0, a0); DOT12(s0, a1, a1); DOT12(s0, a2, a2);
            DOT12(s1, e0, e0); DOT12(s1, e1, e1); DOT12(s1, e2, e2);
            DOT12(s2, f0, f0); DOT12(s2, f1, f1); DOT12(s2, f2, f2);
            DOT12(s3, g0, g0); DOT12(s3, g1, g1); DOT12(s3, g2, g2);
            float d0 = 0.f, d1 = 0.f, d2 = 0.f, d3 = 0.f;
            DOT12(d0, q0, a0); DOT12(d0, q1, a1); DOT12(d0, q2, a2);
            DOT12(d1, q0, e0); DOT12(d1, q1, e1); DOT12(d1, q2, e2);
            DOT12(d2, q0, f0); DOT12(d2, q1, f1); DOT12(d2, q2, f2);
            DOT12(d3, q0, g0); DOT12(d3, q1, g1); DOT12(d3, q2, g2);
            for (int off = 1; off < 64; off <<= 1) {
                s0 += __shfl_xor(s0, off); s1 += __shfl_xor(s1, off);
                s2 += __shfl_xor(s2, off); s3 += __shfl_xor(s3, off);
                d0 += __shfl_xor(d0, off); d1 += __shfl_xor(d1, off);
                d2 += __shfl_xor(d2, off); d3 += __shfl_xor(d3, off);
            }
            if (lane == 0) {
                float* outp = cosall + (size_t)sidx * NPC + n;
                outp[0] = d0 / fmaxf(sqrtf(s0), 1e-12f);
                outp[1] = d1 / fmaxf(sqrtf(s1), 1e-12f);
                outp[2] = d2 / fmaxf(sqrtf(s2), 1e-12f);
                outp[3] = d3 / fmaxf(sqrtf(s3), 1e-12f);
            }
        }
    }
}

// ---------- Kernel E: per-query top-K + id write + embedding gather ----------
__global__ void ktop_final(const float* __restrict__ cosall, const int* __restrict__ cidx,
                           const int* __restrict__ clusted, const float* __restrict__ data,
                           float* __restrict__ out) {
    int b = blockIdx.x, t = threadIdx.x;
    int wave = t >> 6, lane = t & 63;
    __shared__ float vals[NS * NPC];
    __shared__ float wrv[4];
    __shared__ int   wri[4];
    __shared__ int   docs[TOPK];
    for (int i = t; i < NS * NPC; i += 256) vals[i] = cosall[(size_t)b * (NS * NPC) + i];
    __syncthreads();
    for (int j = 0; j < TOPK; ++j) {
        float bv = NEG_INF; int bi = 0x7fffffff;
        for (int i = t; i < NS * NPC; i += 256) {
            float v = vals[i];
            if (v > bv) { bv = v; bi = i; }
        }
        wave_argmax(bv, bi);
        if (lane == 0) { wrv[wave] = bv; wri[wave] = bi; }
        __syncthreads();
        if (t == 0) {
            float fv = wrv[0]; int fi = wri[0];
            for (int w = 1; w < 4; ++w) {
                float v2 = wrv[w]; int i2 = wri[w];
                if (v2 > fv || (v2 == fv && i2 < fi)) { fv = v2; fi = i2; }
            }
            int s = fi >> 8, n = fi & (NPC - 1);
            int c = cidx[b * NS + s];
            int doc = c * NPC + n;
            docs[j] = doc;
            out[b * TOPK + j] = (float)clusted[doc];   // ids < 2^24, exact in f32
            vals[fi] = NEG_INF;
        }
        __syncthreads();
    }
    float* emb = out + BQ * TOPK;
    for (int idx = t; idx < TOPK * (DIM / 4); idx += 256) {
        int j = idx / (DIM / 4), col = idx - j * (DIM / 4);
        int doc = docs[j];
        ((float4*)(emb + ((size_t)(b * TOPK + j)) * DIM))[col] =
            ((const float4*)(data + (size_t)doc * DIM))[col];
    }
}

extern "C" void kernel_launch(void* const* d_in, const int* in_sizes, int n_in,
                              void* d_out, int out_size, void* d_ws, size_t ws_size,
                              hipStream_t stream) {
    const float* querys  = (const float*)d_in[0];   // (64, 768)
    const float* data    = (const float*)d_in[1];   // (1000, 256, 768)
    const float* centers = (const float*)d_in[2];   // (1000, 768)
    const int*   clusted = (const int*)d_in[3];     // (1000, 256)
    float* out = (float*)d_out;                     // [64*16 ids as float][64*16*768 emb]

    float* ws     = (float*)d_ws;
    float* qn     = ws;                              // 64*768
    float* cosc   = qn + BQ * DIM;                   // 64*1000
    int*   cidx   = (int*)(cosc + BQ * KC);          // 64*10
    float* cosall = (float*)(cidx + BQ * NS);        // 64*2560
    int*   cnt    = (int*)(cosall + BQ * NS * NPC);  // 1000
    int*   sel    = cnt + KC;                        // 1000*64

    knorm_q<<<BQ, 256, 0, stream>>>(querys, qn, cnt);
    kcenter_scores<<<KC, 256, 0, stream>>>(qn, centers, cosc);
    ktop_clusters<<<BQ, 256, 0, stream>>>(cosc, cidx, cnt, sel);
    kcand<<<KC * 4, 256, 0, stream>>>(qn, data, cnt, sel, cosall);
    ktop_final<<<BQ, 256, 0, stream>>>(cosall, cidx, clusted, data, out);
}

// Round 10
// 132.804 us; speedup vs baseline: 3.8527x; 1.0401x over previous
//
#include <hip/hip_runtime.h>
#include <math.h>

// Problem constants: B=64, K=1000, NPC=256, D=768, k=16, S=10
#define BQ   64
#define KC   1000
#define NPC  256
#define DIM  768
#define TOPK 16
#define NS   10

#define NEG_INF (-__builtin_inff())

#define DOT12(acc, A, Bv) \
    acc = fmaf(A.x, Bv.x, acc); acc = fmaf(A.y, Bv.y, acc); \
    acc = fmaf(A.z, Bv.z, acc); acc = fmaf(A.w, Bv.w, acc);

// NOTE: query normalization (old kernel A) is dropped. score = dot(q_raw,x)/|x|
// = |q| * cos(q,x): a uniform positive per-query scale, so every per-query
// top-k (clusters in C, docs in E) is unchanged. Outputs (ids, raw embeddings)
// never expose scores. Validated on-device in rounds 5 & 6.

// ---------- Kernel B: cosc[b][k] = dot(q[b], centers[k]) / |centers[k]| ----------
// grid = 1000 blocks: (250 center-quads) x (4 query-groups of 16). One wave per
// center. Block i also zeroes cnt[i] (grid == KC).
__global__ void kcenter_scores(const float* __restrict__ q,
                               const float* __restrict__ centers,
                               float* __restrict__ cosc,
                               int* __restrict__ cnt) {
    if (threadIdx.x == 0) cnt[blockIdx.x] = 0;
    int wave = threadIdx.x >> 6, lane = threadIdx.x & 63;
    int cblk = blockIdx.x >> 2, qg = blockIdx.x & 3;
    int k0 = cblk * 4 + wave;                    // 250*4 = 1000 exactly
    const float4* cp = (const float4*)(centers + (size_t)k0 * DIM);
    float4 c0 = cp[lane], c1 = cp[lane + 64], c2 = cp[lane + 128];
    float sq = 0.f;
    DOT12(sq, c0, c0); DOT12(sq, c1, c1); DOT12(sq, c2, c2);
    for (int off = 1; off < 64; off <<= 1) sq += __shfl_xor(sq, off);
    float inv = 1.0f / fmaxf(sqrtf(sq), 1e-12f);
    int b0 = qg * 16;
    for (int i = 0; i < 16; i += 4) {
        const float4* qa = (const float4*)(q + (size_t)(b0 + i + 0) * DIM);
        const float4* qb = (const float4*)(q + (size_t)(b0 + i + 1) * DIM);
        const float4* qc = (const float4*)(q + (size_t)(b0 + i + 2) * DIM);
        const float4* qd = (const float4*)(q + (size_t)(b0 + i + 3) * DIM);
        float4 a0 = qa[lane], a1 = qa[lane + 64], a2 = qa[lane + 128];
        float4 e0 = qb[lane], e1 = qb[lane + 64], e2 = qb[lane + 128];
        float4 f0 = qc[lane], f1 = qc[lane + 64], f2 = qc[lane + 128];
        float4 g0 = qd[lane], g1 = qd[lane + 64], g2 = qd[lane + 128];
        float dA = 0.f, dB = 0.f, dC = 0.f, dD = 0.f;
        DOT12(dA, a0, c0); DOT12(dA, a1, c1); DOT12(dA, a2, c2);
        DOT12(dB, e0, c0); DOT12(dB, e1, c1); DOT12(dB, e2, c2);
        DOT12(dC, f0, c0); DOT12(dC, f1, c1); DOT12(dC, f2, c2);
        DOT12(dD, g0, c0); DOT12(dD, g1, c1); DOT12(dD, g2, c2);
        for (int off = 1; off < 64; off <<= 1) {
            dA += __shfl_xor(dA, off);
            dB += __shfl_xor(dB, off);
            dC += __shfl_xor(dC, off);
            dD += __shfl_xor(dD, off);
        }
        if (lane == 0) {
            cosc[(b0 + i + 0) * KC + k0] = dA * inv;
            cosc[(b0 + i + 1) * KC + k0] = dB * inv;
            cosc[(b0 + i + 2) * KC + k0] = dC * inv;
            cosc[(b0 + i + 3) * KC + k0] = dD * inv;
        }
    }
}

// ---------- wave argmax: ties -> smaller index (matches jax.lax.top_k) ----------
__device__ __forceinline__ void wave_argmax(float& bv, int& bi) {
    for (int off = 1; off < 64; off <<= 1) {
        float v2 = __shfl_xor(bv, off);
        int   i2 = __shfl_xor(bi, off);
        if (v2 > bv || (v2 == bv && i2 < bi)) { bv = v2; bi = i2; }
    }
}

// ---------- Kernel C: per-query top-NS clusters + inverted cluster->selector map ----------
__global__ void ktop_clusters(const float* __restrict__ cosc, int* __restrict__ cidx,
                              int* __restrict__ cnt, int* __restrict__ sel) {
    int b = blockIdx.x, t = threadIdx.x;
    int wave = t >> 6, lane = t & 63;
    __shared__ float vals[KC];
    __shared__ float wrv[4];
    __shared__ int   wri[4];
    for (int i = t; i < KC; i += 256) vals[i] = cosc[b * KC + i];
    __syncthreads();
    for (int s = 0; s < NS; ++s) {
        float bv = NEG_INF; int bi = 0x7fffffff;
        for (int i = t; i < KC; i += 256) {
            float v = vals[i];
            if (v > bv) { bv = v; bi = i; }
        }
        wave_argmax(bv, bi);
        if (lane == 0) { wrv[wave] = bv; wri[wave] = bi; }
        __syncthreads();
        if (t == 0) {
            float fv = wrv[0]; int fi = wri[0];
            for (int w = 1; w < 4; ++w) {
                float v2 = wrv[w]; int i2 = wri[w];
                if (v2 > fv || (v2 == fv && i2 < fi)) { fv = v2; fi = i2; }
            }
            cidx[b * NS + s] = fi;
            int pos = atomicAdd(&cnt[fi], 1);     // device-scope
            sel[fi * 64 + pos] = b * NS + s;
            vals[fi] = NEG_INF;
        }
        __syncthreads();
    }
}

// ---------- Kernel D: vmcnt-clean software-pipelined candidate cosines ----------
// At the measured cold-read roofline (~3.1 TB/s): 364 MB distinct -> ~117 us.
#define QROWS 15

#define LOADB(buf, itv) do {                                                   \
    int nb_ = n0 + (itv) * 4;                                                  \
    const float4* dp0_ = (const float4*)(base + (size_t)(nb_ + 0) * DIM);      \
    const float4* dp1_ = (const float4*)(base + (size_t)(nb_ + 1) * DIM);      \
    const float4* dp2_ = (const float4*)(base + (size_t)(nb_ + 2) * DIM);      \
    const float4* dp3_ = (const float4*)(base + (size_t)(nb_ + 3) * DIM);      \
    buf[0] = dp0_[lane]; buf[1]  = dp0_[lane + 64]; buf[2]  = dp0_[lane + 128];\
    buf[3] = dp1_[lane]; buf[4]  = dp1_[lane + 64]; buf[5]  = dp1_[lane + 128];\
    buf[6] = dp2_[lane]; buf[7]  = dp2_[lane + 64]; buf[8]  = dp2_[lane + 128];\
    buf[9] = dp3_[lane]; buf[10] = dp3_[lane + 64]; buf[11] = dp3_[lane + 128];\
} while (0)

#define PROCB(buf, itv) do {                                                   \
    float s0 = 0.f, s1 = 0.f, s2 = 0.f, s3 = 0.f;                              \
    DOT12(s0, buf[0], buf[0]); DOT12(s0, buf[1], buf[1]); DOT12(s0, buf[2], buf[2]); \
    DOT12(s1, buf[3], buf[3]); DOT12(s1, buf[4], buf[4]); DOT12(s1, buf[5], buf[5]); \
    DOT12(s2, buf[6], buf[6]); DOT12(s2, buf[7], buf[7]); DOT12(s2, buf[8], buf[8]); \
    DOT12(s3, buf[9], buf[9]); DOT12(s3, buf[10], buf[10]); DOT12(s3, buf[11], buf[11]); \
    for (int off = 1; off < 64; off <<= 1) {                                   \
        s0 += __shfl_xor(s0, off); s1 += __shfl_xor(s1, off);                  \
        s2 += __shfl_xor(s2, off); s3 += __shfl_xor(s3, off);                  \
    }                                                                          \
    float i0 = 1.0f / fmaxf(sqrtf(s0), 1e-12f);                                \
    float i1 = 1.0f / fmaxf(sqrtf(s1), 1e-12f);                                \
    float i2 = 1.0f / fmaxf(sqrtf(s2), 1e-12f);                                \
    float i3 = 1.0f / fmaxf(sqrtf(s3), 1e-12f);                                \
    for (int j = 0; j < mq; ++j) {                                             \
        float4 q0 = *(const float4*)&qlds[j * DIM + lane * 4];                 \
        float4 q1 = *(const float4*)&qlds[j * DIM + (lane + 64) * 4];          \
        float4 q2 = *(const float4*)&qlds[j * DIM + (lane + 128) * 4];         \
        float d0 = 0.f, d1 = 0.f, d2 = 0.f, d3 = 0.f;                          \
        DOT12(d0, q0, buf[0]); DOT12(d0, q1, buf[1]); DOT12(d0, q2, buf[2]);   \
        DOT12(d1, q0, buf[3]); DOT12(d1, q1, buf[4]); DOT12(d1, q2, buf[5]);   \
        DOT12(d2, q0, buf[6]); DOT12(d2, q1, buf[7]); DOT12(d2, q2, buf[8]);   \
        DOT12(d3, q0, buf[9]); DOT12(d3, q1, buf[10]); DOT12(d3, q2, buf[11]); \
        for (int off = 1; off < 64; off <<= 1) {                               \
            d0 += __shfl_xor(d0, off); d1 += __shfl_xor(d1, off);              \
            d2 += __shfl_xor(d2, off); d3 += __shfl_xor(d3, off);              \
        }                                                                      \
        if (lane == 0) {                                                       \
            res[wave][j][(itv) * 4 + 0] = d0 * i0;                             \
            res[wave][j][(itv) * 4 + 1] = d1 * i1;                             \
            res[wave][j][(itv) * 4 + 2] = d2 * i2;                             \
            res[wave][j][(itv) * 4 + 3] = d3 * i3;                             \
        }                                                                      \
    }                                                                          \
} while (0)

__global__ __launch_bounds__(256, 3) void kcand(const float* __restrict__ q,
                                                const float* __restrict__ data,
                                                const int* __restrict__ cnt,
                                                const int* __restrict__ sel,
                                                float* __restrict__ cosall) {
    int c = blockIdx.x >> 2, sub = blockIdx.x & 3;
    int m = cnt[c];
    if (m == 0) return;
    int t = threadIdx.x;
    __shared__ int   slist[64];
    __shared__ float qlds[QROWS * DIM];          // 45 KB
    __shared__ float res[4][QROWS][16];          // 3.75 KB
    if (t < m) slist[t] = sel[c * 64 + t];
    __syncthreads();
    int mq = min(m, QROWS);
    for (int j = 0; j < mq; ++j) {
        int brow = slist[j] / NS;
        const float4* src = (const float4*)(q + (size_t)brow * DIM);
        float4* dst = (float4*)&qlds[j * DIM];
        for (int idx = t; idx < DIM / 4; idx += 256) dst[idx] = src[idx];
    }
    __syncthreads();   // clean vmcnt slate before the pipelined region
    int wave = t >> 6, lane = t & 63;
    const float* base = data + (size_t)c * NPC * DIM;
    int n0 = sub * 64 + wave * 16;

    float4 bufA[12], bufB[12];
    LOADB(bufA, 0);
    LOADB(bufB, 1);     // 24 loads in flight
    PROCB(bufA, 0);     // vmem-free compute: bufB stays in flight
    LOADB(bufA, 2);
    PROCB(bufB, 1);
    LOADB(bufB, 3);
    PROCB(bufA, 2);
    PROCB(bufB, 3);

    // flush buffered results (coalesced 64B segments)
    for (int idx = lane; idx < mq * 16; idx += 64) {
        int j = idx >> 4, nn = idx & 15;
        cosall[(size_t)slist[j] * NPC + n0 + nn] = res[wave][j][nn];
    }

    // rare epilogue: selectors beyond QROWS (recompute from L2-warm data)
    for (int j = QROWS; j < m; ++j) {
        int sidx = slist[j];
        int brow = sidx / NS;
        const float4* qp = (const float4*)(q + (size_t)brow * DIM);
        float4 q0 = qp[lane], q1 = qp[lane + 64], q2 = qp[lane + 128];
        for (int it = 0; it < 4; ++it) {
            int n = n0 + it * 4;
            const float4* dp0 = (const float4*)(base + (size_t)(n + 0) * DIM);
            const float4* dp1 = (const float4*)(base + (size_t)(n + 1) * DIM);
            const float4* dp2 = (const float4*)(base + (size_t)(n + 2) * DIM);
            const float4* dp3 = (const float4*)(base + (size_t)(n + 3) * DIM);
            float4 a0 = dp0[lane], a1 = dp0[lane + 64], a2 = dp0[lane + 128];
            float4 e0 = dp1[lane], e1 = dp1[lane + 64], e2 = dp1[lane + 128];
            float4 f0 = dp2[lane], f1 = dp2[lane + 64], f2 = dp2[lane + 128];
            float4 g0 = dp3[lane], g1 = dp3[lane + 64], g2 = dp3[lane + 128];
            float s0 = 0.f, s1 = 0.f, s2 = 0.f, s3 = 0.f;
            DOT12(s0, a0, a0); DOT12(s0, a1, a1); DOT12(s0, a2, a2);
            DOT12(s1, e0, e0); DOT12(s1, e1, e1); DOT12(s1, e2, e2);
            DOT12(s2, f0, f0); DOT12(s2, f1, f1); DOT12(s2, f2, f2);
            DOT12(s3, g0, g0); DOT12(s3, g1, g1); DOT12(s3, g2, g2);
            float d0 = 0.f, d1 = 0.f, d2 = 0.f, d3 = 0.f;
            DOT12(d0, q0, a0); DOT12(d0, q1, a1); DOT12(d0, q2, a2);
            DOT12(d1, q0, e0); DOT12(d1, q1, e1); DOT12(d1, q2, e2);
            DOT12(d2, q0, f0); DOT12(d2, q1, f1); DOT12(d2, q2, f2);
            DOT12(d3, q0, g0); DOT12(d3, q1, g1); DOT12(d3, q2, g2);
            for (int off = 1; off < 64; off <<= 1) {
                s0 += __shfl_xor(s0, off); s1 += __shfl_xor(s1, off);
                s2 += __shfl_xor(s2, off); s3 += __shfl_xor(s3, off);
                d0 += __shfl_xor(d0, off); d1 += __shfl_xor(d1, off);
                d2 += __shfl_xor(d2, off); d3 += __shfl_xor(d3, off);
            }
            if (lane == 0) {
                float* outp = cosall + (size_t)sidx * NPC + n;
                outp[0] = d0 / fmaxf(sqrtf(s0), 1e-12f);
                outp[1] = d1 / fmaxf(sqrtf(s1), 1e-12f);
                outp[2] = d2 / fmaxf(sqrtf(s2), 1e-12f);
                outp[3] = d3 / fmaxf(sqrtf(s3), 1e-12f);
            }
        }
    }
}

// ---------- Kernel E: per-query top-K + id write + embedding gather ----------
__global__ void ktop_final(const float* __restrict__ cosall, const int* __restrict__ cidx,
                           const int* __restrict__ clusted, const float* __restrict__ data,
                           float* __restrict__ out) {
    int b = blockIdx.x, t = threadIdx.x;
    int wave = t >> 6, lane = t & 63;
    __shared__ float vals[NS * NPC];
    __shared__ float wrv[4];
    __shared__ int   wri[4];
    __shared__ int   docs[TOPK];
    for (int i = t; i < NS * NPC; i += 256) vals[i] = cosall[(size_t)b * (NS * NPC) + i];
    __syncthreads();
    for (int j = 0; j < TOPK; ++j) {
        float bv = NEG_INF; int bi = 0x7fffffff;
        for (int i = t; i < NS * NPC; i += 256) {
            float v = vals[i];
            if (v > bv) { bv = v; bi = i; }
        }
        wave_argmax(bv, bi);
        if (lane == 0) { wrv[wave] = bv; wri[wave] = bi; }
        __syncthreads();
        if (t == 0) {
            float fv = wrv[0]; int fi = wri[0];
            for (int w = 1; w < 4; ++w) {
                float v2 = wrv[w]; int i2 = wri[w];
                if (v2 > fv || (v2 == fv && i2 < fi)) { fv = v2; fi = i2; }
            }
            int s = fi >> 8, n = fi & (NPC - 1);
            int c = cidx[b * NS + s];
            int doc = c * NPC + n;
            docs[j] = doc;
            out[b * TOPK + j] = (float)clusted[doc];   // ids < 2^24, exact in f32
            vals[fi] = NEG_INF;
        }
        __syncthreads();
    }
    float* emb = out + BQ * TOPK;
    for (int idx = t; idx < TOPK * (DIM / 4); idx += 256) {
        int j = idx / (DIM / 4), col = idx - j * (DIM / 4);
        int doc = docs[j];
        ((float4*)(emb + ((size_t)(b * TOPK + j)) * DIM))[col] =
            ((const float4*)(data + (size_t)doc * DIM))[col];
    }
}

extern "C" void kernel_launch(void* const* d_in, const int* in_sizes, int n_in,
                              void* d_out, int out_size, void* d_ws, size_t ws_size,
                              hipStream_t stream) {
    const float* querys  = (const float*)d_in[0];   // (64, 768)
    const float* data    = (const float*)d_in[1];   // (1000, 256, 768)
    const float* centers = (const float*)d_in[2];   // (1000, 768)
    const int*   clusted = (const int*)d_in[3];     // (1000, 256)
    float* out = (float*)d_out;                     // [64*16 ids as float][64*16*768 emb]

    float* ws     = (float*)d_ws;
    float* cosc   = ws;                              // 64*1000
    int*   cidx   = (int*)(cosc + BQ * KC);          // 64*10
    float* cosall = (float*)(cidx + BQ * NS);        // 64*2560
    int*   cnt    = (int*)(cosall + BQ * NS * NPC);  // 1000
    int*   sel    = cnt + KC;                        // 1000*64

    kcenter_scores<<<KC, 256, 0, stream>>>(querys, centers, cosc, cnt);
    ktop_clusters<<<BQ, 256, 0, stream>>>(cosc, cidx, cnt, sel);
    kcand<<<KC * 4, 256, 0, stream>>>(querys, data, cnt, sel, cosall);
    ktop_final<<<BQ, 256, 0, stream>>>(cosall, cidx, clusted, data, out);
}